// Round 4
// baseline (469.741 us; speedup 1.0000x reference)
//
#include <hip/hip_runtime.h>
#include <hip/hip_fp16.h>
#include <math.h>

#define N_NODES 50000
#define N_EDGES 1600000
#define DIM 128
#define HEADS 8
#define NEG_SLOPE 0.2f
#define BN_EPS 1e-5f

typedef _Float16 f16x8 __attribute__((ext_vector_type(8)));
typedef float f32x4 __attribute__((ext_vector_type(4)));

// ---------------------------------------------------------------------------
// Grid constants. K1 is heterogeneous: first CNT_NB blocks count degrees,
// remaining LIN_NB blocks do the MFMA linear transform.
// ---------------------------------------------------------------------------
#define CHUNK 8192
#define CNT_NB ((N_EDGES + CHUNK - 1) / CHUNK)  // 196
#define LIN_NB ((N_NODES + 127) / 128)           // 391 (8 waves x 16 nodes)
#define FUSED_NB (CNT_NB + LIN_NB)               // 587

// ---------------------------------------------------------------------------
// K1: heterogeneous fused kernel, 512 threads/block.
//   blocks [0, CNT_NB):      count — atomicAdd(deg[dst]) per edge. deg is
//                            200 KB, L2-resident; ~32 hits/counter total.
//   blocks [CNT_NB, FUSED_NB): lin — xl = x @ W via MFMA 16x16x32 f16 with
//                            W swizzled fp32->fp16 into LDS per block;
//                            fused per-head attention dots (pre-scaled 1/ln2).
// The two halves are data-independent; co-residency lets MFMA-heavy lin
// waves and atomic-heavy count waves share CUs.
// ---------------------------------------------------------------------------
struct LinShm { __half wh[16384]; };        // 32 KB

__global__ __launch_bounds__(512) void k_linbinA(
        const float* __restrict__ x, const float* __restrict__ W,
        const float* __restrict__ att_s, const float* __restrict__ att_d,
        const int* __restrict__ ei, int* __restrict__ deg,
        __half* __restrict__ xlh,
        float* __restrict__ a_src, float* __restrict__ a_dst) {
    __shared__ LinShm sh;
    const int t = threadIdx.x;

    if (blockIdx.x < CNT_NB) {
        // ----- count -----
        const int base = blockIdx.x * CHUNK;
        const int cnt = min(CHUNK, N_EDGES - base);   // multiple of 4
        for (int i = t * 4; i < cnt; i += 2048) {
            const int4 dv = *(const int4*)(ei + N_EDGES + base + i);
            atomicAdd(&deg[dv.x], 1);
            atomicAdd(&deg[dv.y], 1);
            atomicAdd(&deg[dv.z], 1);
            atomicAdd(&deg[dv.w], 1);
        }
    } else {
        // ----- lin -----
        // stage W into LDS, swizzled to MFMA B-fragment order, fp16.
        // frag g=nt*4+kt: lane holds B[k=kt*32+q*8+j][n=nt*16+(lane&15)]
        for (int v = t; v < 2048; v += 512) {
            const int g = v >> 6, lane = v & 63;
            const int nt = g >> 2, kt = g & 3;
            const int q = lane >> 4, n = lane & 15;
            #pragma unroll
            for (int j = 0; j < 8; ++j)
                sh.wh[(size_t)(g * 64 + lane) * 8 + j] =
                    __float2half(W[(kt * 32 + q * 8 + j) * DIM + nt * 16 + n]);
        }
        __syncthreads();

        const int wave = t >> 6;
        const int lane = t & 63;
        const int q = lane >> 4, n = lane & 15;
        const int nb = ((blockIdx.x - CNT_NB) * 8 + wave) * 16;

        const int rowA = min(nb + n, N_NODES - 1);
        const float* xr = x + (size_t)rowA * DIM;
        f16x8 a[4];
        #pragma unroll
        for (int kt = 0; kt < 4; ++kt) {
            const float4 p0 = *(const float4*)(xr + kt * 32 + q * 8);
            const float4 p1 = *(const float4*)(xr + kt * 32 + q * 8 + 4);
            a[kt][0] = (_Float16)p0.x; a[kt][1] = (_Float16)p0.y;
            a[kt][2] = (_Float16)p0.z; a[kt][3] = (_Float16)p0.w;
            a[kt][4] = (_Float16)p1.x; a[kt][5] = (_Float16)p1.y;
            a[kt][6] = (_Float16)p1.z; a[kt][7] = (_Float16)p1.w;
        }

        f32x4 acc[8];
        #pragma unroll
        for (int nt = 0; nt < 8; ++nt) acc[nt] = (f32x4){0.f, 0.f, 0.f, 0.f};

        const f16x8* wb = (const f16x8*)sh.wh;
        #pragma unroll
        for (int nt = 0; nt < 8; ++nt) {
            #pragma unroll
            for (int kt = 0; kt < 4; ++kt) {
                const f16x8 b = wb[(nt * 4 + kt) * 64 + lane];
                acc[nt] = __builtin_amdgcn_mfma_f32_16x16x32_f16(a[kt], b, acc[nt], 0, 0, 0);
            }
        }

        const int r0 = nb + q * 4;
        #pragma unroll
        for (int nt = 0; nt < 8; ++nt) {
            const float as = att_s[nt * 16 + n];
            const float ad = att_d[nt * 16 + n];
            #pragma unroll
            for (int r = 0; r < 4; ++r) {
                const int row = r0 + r;
                const float v = acc[nt][r];
                float s = v * as;
                float d = v * ad;
                #pragma unroll
                for (int off = 8; off; off >>= 1) {
                    s += __shfl_xor(s, off, 16);
                    d += __shfl_xor(d, off, 16);
                }
                if (row < N_NODES) {
                    xlh[(size_t)row * DIM + nt * 16 + n] = __float2half(v);
                    if (n == 0) {
                        // fold 1/ln2 into the attention logits so the edge
                        // kernel can use a bare exp2 (leaky-relu commutes
                        // with positive scaling).
                        a_src[row * HEADS + nt] = s * 1.44269504f;
                        a_dst[row * HEADS + nt] = d * 1.44269504f;
                    }
                }
            }
        }
    }
}

// ---------------------------------------------------------------------------
// K2: single-block two-level exclusive scan over deg[50000].
// Thread t serially sums its 49-node chunk, block-scans the 1024 partials,
// then re-walks the chunk emitting nrange=(start,end) and cursor=start.
// ---------------------------------------------------------------------------
#define SCAN_T 1024
#define NODES_PER_T ((N_NODES + SCAN_T - 1) / SCAN_T)   // 49

__global__ __launch_bounds__(1024) void k_scan(const int* __restrict__ deg,
                                               int* __restrict__ cursor,
                                               int2* __restrict__ nrange) {
    __shared__ int part[SCAN_T];
    const int t = threadIdx.x;
    const int b0 = t * NODES_PER_T;
    const int b1 = min(b0 + NODES_PER_T, N_NODES);
    int s = 0;
    for (int i = b0; i < b1; ++i) s += deg[i];
    part[t] = s;
    __syncthreads();
    for (int d = 1; d < SCAN_T; d <<= 1) {
        int xo = 0;
        if (t >= d) xo = part[t - d];
        __syncthreads();
        part[t] += xo;
        __syncthreads();
    }
    int run = part[t] - s;                  // exclusive prefix of this chunk
    for (int i = b0; i < b1; ++i) {
        const int dg = deg[i];
        int2 rg; rg.x = run; rg.y = run + dg;
        nrange[i] = rg;
        cursor[i] = run;
        run += dg;
    }
}

// ---------------------------------------------------------------------------
// K2b: atomic scatter. pos = atomicAdd(cursor[dst]); csr[pos] = (ushort)src.
// Order within a node's list is arbitrary — softmax aggregation is
// order-invariant. 2B stores at byte granularity merge correctly across
// XCDs (dirty-byte-mask writeback; same pattern as rocPRIM scatter).
// ---------------------------------------------------------------------------
#define SCAT_NB ((N_EDGES / 4 + 511) / 512)   // 782

__global__ __launch_bounds__(512) void k_scatter(const int* __restrict__ ei,
                                                 int* __restrict__ cursor,
                                                 unsigned short* __restrict__ csr) {
    const int i = (blockIdx.x * 512 + threadIdx.x) * 4;
    if (i >= N_EDGES) return;
    const int4 sv = *(const int4*)(ei + i);
    const int4 dv = *(const int4*)(ei + N_EDGES + i);
    const int p0 = atomicAdd(&cursor[dv.x], 1);
    const int p1 = atomicAdd(&cursor[dv.y], 1);
    const int p2 = atomicAdd(&cursor[dv.z], 1);
    const int p3 = atomicAdd(&cursor[dv.w], 1);
    csr[p0] = (unsigned short)sv.x;
    csr[p1] = (unsigned short)sv.y;
    csr[p2] = (unsigned short)sv.z;
    csr[p3] = (unsigned short)sv.w;
}

// ---------------------------------------------------------------------------
// K3 v9 (unchanged, proven 61 µs): fused softmax + aggregation. One node per
// wave, 4 edge-groups x 16 lanes, lane covers 8 channels via one f16x8
// gather; 16-edge main loop (4 independent dependent-chains in flight).
// Logits pre-scaled by 1/ln2 -> bare exp2f. Butterfly (xor 16,32) recombine;
// coalesced float2 full-row write.
// ---------------------------------------------------------------------------
#define AGG_NB (N_NODES / 4)   // 12500

__global__ void k_aggr9(const int2* __restrict__ nrange,
                        const unsigned short* __restrict__ csr,
                        const float* __restrict__ a_src, const float* __restrict__ a_dst,
                        const __half* __restrict__ xlh, float* __restrict__ y) {
    const int d = blockIdx.x * 4 + (threadIdx.x >> 6);
    const int lane = threadIdx.x & 63;
    const int g = lane >> 4;        // edge sub-group 0..3
    const int cl = lane & 15;       // channel slot: channels [cl*8, cl*8+8)
    const int h = cl >> 1;          // head owning this slot (OUT_C=16)
    const int2 rg = nrange[d];
    const int lo = rg.x, hi = rg.y;
    const float ad = a_dst[d * HEADS + h];

    float acc[8];
    #pragma unroll
    for (int k = 0; k < 8; ++k) acc[k] = 0.f;
    float dsum = 0.f;

    int i = lo;
    // 16 edges per iteration: 4 independent 4-edge batches
    for (; i + 16 <= hi; i += 16) {
        const int s0 = csr[i + g];
        const int s1 = csr[i + 4 + g];
        const int s2 = csr[i + 8 + g];
        const int s3 = csr[i + 12 + g];
        const float as0 = a_src[s0 * HEADS + h];
        const float as1 = a_src[s1 * HEADS + h];
        const float as2 = a_src[s2 * HEADS + h];
        const float as3 = a_src[s3 * HEADS + h];
        const f16x8 x0 = *(const f16x8*)(xlh + (size_t)s0 * DIM + cl * 8);
        const f16x8 x1 = *(const f16x8*)(xlh + (size_t)s1 * DIM + cl * 8);
        const f16x8 x2 = *(const f16x8*)(xlh + (size_t)s2 * DIM + cl * 8);
        const f16x8 x3 = *(const f16x8*)(xlh + (size_t)s3 * DIM + cl * 8);
        const float e0 = as0 + ad;
        const float e1 = as1 + ad;
        const float e2 = as2 + ad;
        const float e3 = as3 + ad;
        const float w0 = exp2f(fmaxf(e0, NEG_SLOPE * e0));
        const float w1 = exp2f(fmaxf(e1, NEG_SLOPE * e1));
        const float w2 = exp2f(fmaxf(e2, NEG_SLOPE * e2));
        const float w3 = exp2f(fmaxf(e3, NEG_SLOPE * e3));
        dsum += (w0 + w1) + (w2 + w3);
        #pragma unroll
        for (int k = 0; k < 8; ++k) acc[k] = fmaf(w0, (float)x0[k], acc[k]);
        #pragma unroll
        for (int k = 0; k < 8; ++k) acc[k] = fmaf(w1, (float)x1[k], acc[k]);
        #pragma unroll
        for (int k = 0; k < 8; ++k) acc[k] = fmaf(w2, (float)x2[k], acc[k]);
        #pragma unroll
        for (int k = 0; k < 8; ++k) acc[k] = fmaf(w3, (float)x3[k], acc[k]);
    }
    for (; i + 8 <= hi; i += 8) {
        const int s0 = csr[i + g];
        const int s1 = csr[i + 4 + g];
        const float as0 = a_src[s0 * HEADS + h];
        const float as1 = a_src[s1 * HEADS + h];
        const f16x8 x0 = *(const f16x8*)(xlh + (size_t)s0 * DIM + cl * 8);
        const f16x8 x1 = *(const f16x8*)(xlh + (size_t)s1 * DIM + cl * 8);
        const float e0 = as0 + ad;
        const float e1 = as1 + ad;
        const float w0 = exp2f(fmaxf(e0, NEG_SLOPE * e0));
        const float w1 = exp2f(fmaxf(e1, NEG_SLOPE * e1));
        dsum += w0 + w1;
        #pragma unroll
        for (int k = 0; k < 8; ++k) acc[k] = fmaf(w0, (float)x0[k], acc[k]);
        #pragma unroll
        for (int k = 0; k < 8; ++k) acc[k] = fmaf(w1, (float)x1[k], acc[k]);
    }
    // tail: up to 7 edges, predicated per group (loop bounds wave-uniform)
    for (; i < hi; i += 4) {
        const int idx = i + g;
        const int sv = csr[min(idx, hi - 1)];
        const float e = a_src[sv * HEADS + h] + ad;
        const f16x8 xv = *(const f16x8*)(xlh + (size_t)sv * DIM + cl * 8);
        float w = exp2f(fmaxf(e, NEG_SLOPE * e));
        if (idx >= hi) w = 0.f;
        dsum += w;
        #pragma unroll
        for (int k = 0; k < 8; ++k) acc[k] = fmaf(w, (float)xv[k], acc[k]);
    }
    // cross-group reduce: lanes {l, l^16, l^32, l^48} share channel slot cl
    #pragma unroll
    for (int k = 0; k < 8; ++k) {
        acc[k] += __shfl_xor(acc[k], 16);
        acc[k] += __shfl_xor(acc[k], 32);
    }
    dsum += __shfl_xor(dsum, 16);
    dsum += __shfl_xor(dsum, 32);
    const float inv = 1.f / (dsum + 1e-16f);
    float2 o;
    o.x = acc[2 * g] * inv;
    o.y = acc[2 * g + 1] * inv;
    // lane writes channels cl*8 + 2g, +1: 64 distinct float2 = full row
    *(float2*)(y + (size_t)d * DIM + cl * 8 + g * 2) = o;
}

// ---------------------------------------------------------------------------
// BN stats over h = y + bias (512 blocks x 128 threads)
// ---------------------------------------------------------------------------
__global__ void k_stats(const float* __restrict__ y, const float* __restrict__ bias,
                        float* __restrict__ gsums) {
    const int c = threadIdx.x;
    const float b = bias[c];
    float s = 0.f, ss = 0.f;
    for (int n = blockIdx.x; n < N_NODES; n += gridDim.x) {
        const float h = y[n * DIM + c] + b;
        s += h;
        ss += h * h;
    }
    atomicAdd(&gsums[c], s);
    atomicAdd(&gsums[DIM + c], ss);
}

// ---------------------------------------------------------------------------
// K4: y = x + relu((y + bias - mean) * rsqrt(var+eps) * gamma + beta)
// BN fold computed inline per thread (sums/sumsq L2-resident).
// ---------------------------------------------------------------------------
__global__ void k_final(float* __restrict__ y, const float* __restrict__ x,
                        const float* __restrict__ sums, const float* __restrict__ sumsq,
                        const float* __restrict__ gamma, const float* __restrict__ beta,
                        const float* __restrict__ bias) {
    const int q = blockIdx.x * blockDim.x + threadIdx.x;
    const int cq = q & (DIM / 4 - 1);
    const float4 sm = ((const float4*)sums)[cq];
    const float4 sq = ((const float4*)sumsq)[cq];
    const float4 gm = ((const float4*)gamma)[cq];
    const float4 bt = ((const float4*)beta)[cq];
    const float4 bs = ((const float4*)bias)[cq];
    float4 v = ((const float4*)y)[q];
    const float4 xv = ((const float4*)x)[q];
    const float inv_n = 1.f / (float)N_NODES;
#define BNC(c) { const float mean = sm.c * inv_n;                         \
                 const float var = sq.c * inv_n - mean * mean;            \
                 const float sc = rsqrtf(var + BN_EPS) * gm.c;            \
                 const float sh = bt.c + (bs.c - mean) * sc;              \
                 v.c = xv.c + fmaxf(v.c * sc + sh, 0.f); }
    BNC(x) BNC(y) BNC(z) BNC(w)
#undef BNC
    ((float4*)y)[q] = v;
}

extern "C" void kernel_launch(void* const* d_in, const int* in_sizes, int n_in,
                              void* d_out, int out_size, void* d_ws, size_t ws_size,
                              hipStream_t stream) {
    const float* x     = (const float*)d_in[0];
    const int*   ei    = (const int*)  d_in[1];
    const float* W     = (const float*)d_in[2];
    const float* att_s = (const float*)d_in[3];
    const float* att_d = (const float*)d_in[4];
    const float* bias  = (const float*)d_in[5];
    const float* gamma = (const float*)d_in[6];
    const float* beta  = (const float*)d_in[7];
    float* y = (float*)d_out;

    // workspace layout
    __half* xlh  = (__half*)d_ws;                          // 6,400,000 h (12.8 MB)
    float* a_src = (float*)(xlh + (size_t)N_NODES * DIM);  // 400,000 f
    float* a_dst = a_src + (size_t)N_NODES * HEADS;        // 400,000 f
    float* sums  = a_dst + (size_t)N_NODES * HEADS;        // 128 f
    float* sumsq = sums  + DIM;                            // 128 f
    int*   deg   = (int*)(sumsq + DIM);                    // 50,000 i (memset w/ sums)
    int*   cursor = deg + N_NODES;                         // 50,000 i
    int2*  nrange = (int2*)(cursor + N_NODES);             // 50,000 int2
    unsigned short* csr = (unsigned short*)(nrange + N_NODES); // 1.6M u16 (3.2 MB)

    // zero sums/sumsq (256 f) + deg (50,000 i) in one contiguous memset
    hipMemsetAsync(sums, 0, (size_t)(2 * DIM + N_NODES) * sizeof(int), stream);
    k_linbinA<<<FUSED_NB, 512, 0, stream>>>(x, W, att_s, att_d, ei, deg,
                                            xlh, a_src, a_dst);
    k_scan<<<1, SCAN_T, 0, stream>>>(deg, cursor, nrange);
    k_scatter<<<SCAT_NB, 512, 0, stream>>>(ei, cursor, csr);
    k_aggr9<<<AGG_NB, 256, 0, stream>>>(nrange, csr, a_src, a_dst, xlh, y);
    k_stats<<<512, DIM, 0, stream>>>(y, bias, sums);
    k_final<<<(size_t)N_NODES * DIM / 4 / 256, 256, 0, stream>>>(y, x, sums, sumsq,
                                                                 gamma, beta, bias);
}

// Round 5
// 288.761 us; speedup vs baseline: 1.6267x; 1.6267x over previous
//
#include <hip/hip_runtime.h>
#include <hip/hip_fp16.h>
#include <math.h>

#define N_NODES 50000
#define N_EDGES 1600000
#define DIM 128
#define HEADS 8
#define NEG_SLOPE 0.2f
#define BN_EPS 1e-5f

typedef _Float16 f16x8 __attribute__((ext_vector_type(8)));
typedef float f32x4 __attribute__((ext_vector_type(4)));

// ---------------------------------------------------------------------------
// CSR build constants: bucket b = dst>>8; fixed segment base b*SEGCAP.
// SEGCAP 9216 = bucket mean 8163 + 11 sigma (binomial sigma ~= 90).
// ---------------------------------------------------------------------------
#define NBUCK 196
#define SEGCAP 9216
#define CHUNK 8192
#define NB_A ((N_EDGES + CHUNK - 1) / CHUNK)   // 196
#define LIN_NB ((N_NODES + 127) / 128)          // 391 (8 waves x 16 nodes)
#define FUSED_NB (NB_A + LIN_NB)                // 587

// ---------------------------------------------------------------------------
// K1: heterogeneous fused kernel, 512 threads/block.
//   blocks [0, NB_A):        binA — LDS counting sort of an 8192-edge chunk
//                            by coarse bucket, coalesced segment flush.
//                            ALSO counts exact per-node degrees via
//                            fire-and-forget global atomics (deg[] L2-res).
//   blocks [NB_A, FUSED_NB): lin — xl = x @ W via MFMA 16x16x32 f16 with
//                            W swizzled fp32->fp16 into LDS per block;
//                            fused per-head attention dots (1/ln2 prescale).
// ---------------------------------------------------------------------------
struct BinAShm {
    int hist[NBUCK], excl[NBUCK], gbase[NBUCK], cnt2[NBUCK];
    int sc[256];
    unsigned int buf[CHUNK];                // 32 KB
};
struct LinShm { __half wh[16384]; };        // 32 KB

__global__ __launch_bounds__(512) void k_linbinA(
        const float* __restrict__ x, const float* __restrict__ W,
        const float* __restrict__ att_s, const float* __restrict__ att_d,
        const int* __restrict__ ei, int* __restrict__ bcur,
        int* __restrict__ deg,
        unsigned int* __restrict__ pairs, __half* __restrict__ xlh,
        float* __restrict__ a_src, float* __restrict__ a_dst) {
    __shared__ union { BinAShm a; LinShm l; } sh;
    const int t = threadIdx.x;

    if (blockIdx.x < NB_A) {
        // ----- binA + degree count -----
        const int base = blockIdx.x * CHUNK;
        const int cnt = min(CHUNK, N_EDGES - base);   // multiple of 4

        for (int j = t; j < NBUCK; j += 512) { sh.a.hist[j] = 0; sh.a.cnt2[j] = 0; }
        __syncthreads();
        for (int i = t * 4; i < cnt; i += 2048) {
            const int4 dv = *(const int4*)(ei + N_EDGES + base + i);
            atomicAdd(&sh.a.hist[dv.x >> 8], 1);
            atomicAdd(&sh.a.hist[dv.y >> 8], 1);
            atomicAdd(&sh.a.hist[dv.z >> 8], 1);
            atomicAdd(&sh.a.hist[dv.w >> 8], 1);
            // exact per-node degree (no return value -> fire-and-forget)
            atomicAdd(&deg[dv.x], 1);
            atomicAdd(&deg[dv.y], 1);
            atomicAdd(&deg[dv.z], 1);
            atomicAdd(&deg[dv.w], 1);
        }
        __syncthreads();
        if (t < 256) sh.a.sc[t] = (t < NBUCK) ? sh.a.hist[t] : 0;
        __syncthreads();
        for (int d = 1; d < 256; d <<= 1) {
            int xo = 0;
            if (t < 256 && t >= d) xo = sh.a.sc[t - d];
            __syncthreads();
            if (t < 256) sh.a.sc[t] += xo;
            __syncthreads();
        }
        if (t < NBUCK) {
            sh.a.excl[t] = sh.a.sc[t] - sh.a.hist[t];
            sh.a.gbase[t] = t * SEGCAP + atomicAdd(&bcur[t], sh.a.hist[t]);
        }
        __syncthreads();
        for (int i = t * 4; i < cnt; i += 2048) {
            const int4 sv = *(const int4*)(ei + base + i);
            const int4 dv = *(const int4*)(ei + N_EDGES + base + i);
            const int ss[4] = {sv.x, sv.y, sv.z, sv.w};
            const int dd[4] = {dv.x, dv.y, dv.z, dv.w};
            #pragma unroll
            for (int k = 0; k < 4; ++k) {
                const int b = dd[k] >> 8;
                const int r = atomicAdd(&sh.a.cnt2[b], 1);
                sh.a.buf[sh.a.excl[b] + r] = (unsigned int)ss[k]
                    | ((unsigned int)(dd[k] & 255) << 16) | ((unsigned int)b << 24);
            }
        }
        __syncthreads();
        for (int i = t; i < cnt; i += 512) {
            const unsigned int u = sh.a.buf[i];
            const int b = u >> 24;
            pairs[sh.a.gbase[b] + (i - sh.a.excl[b])] = u & 0xFFFFFF;
        }
    } else {
        // ----- lin -----
        // stage W into LDS, swizzled to MFMA B-fragment order, fp16.
        // frag g=nt*4+kt: lane holds B[k=kt*32+q*8+j][n=nt*16+(lane&15)]
        for (int v = t; v < 2048; v += 512) {
            const int g = v >> 6, lane = v & 63;
            const int nt = g >> 2, kt = g & 3;
            const int q = lane >> 4, n = lane & 15;
            #pragma unroll
            for (int j = 0; j < 8; ++j)
                sh.l.wh[(size_t)(g * 64 + lane) * 8 + j] =
                    __float2half(W[(kt * 32 + q * 8 + j) * DIM + nt * 16 + n]);
        }
        __syncthreads();

        const int wave = t >> 6;
        const int lane = t & 63;
        const int q = lane >> 4, n = lane & 15;
        const int nb = ((blockIdx.x - NB_A) * 8 + wave) * 16;

        const int rowA = min(nb + n, N_NODES - 1);
        const float* xr = x + (size_t)rowA * DIM;
        f16x8 a[4];
        #pragma unroll
        for (int kt = 0; kt < 4; ++kt) {
            const float4 p0 = *(const float4*)(xr + kt * 32 + q * 8);
            const float4 p1 = *(const float4*)(xr + kt * 32 + q * 8 + 4);
            a[kt][0] = (_Float16)p0.x; a[kt][1] = (_Float16)p0.y;
            a[kt][2] = (_Float16)p0.z; a[kt][3] = (_Float16)p0.w;
            a[kt][4] = (_Float16)p1.x; a[kt][5] = (_Float16)p1.y;
            a[kt][6] = (_Float16)p1.z; a[kt][7] = (_Float16)p1.w;
        }

        f32x4 acc[8];
        #pragma unroll
        for (int nt = 0; nt < 8; ++nt) acc[nt] = (f32x4){0.f, 0.f, 0.f, 0.f};

        const f16x8* wb = (const f16x8*)sh.l.wh;
        #pragma unroll
        for (int nt = 0; nt < 8; ++nt) {
            #pragma unroll
            for (int kt = 0; kt < 4; ++kt) {
                const f16x8 b = wb[(nt * 4 + kt) * 64 + lane];
                acc[nt] = __builtin_amdgcn_mfma_f32_16x16x32_f16(a[kt], b, acc[nt], 0, 0, 0);
            }
        }

        const int r0 = nb + q * 4;
        #pragma unroll
        for (int nt = 0; nt < 8; ++nt) {
            const float as = att_s[nt * 16 + n];
            const float ad = att_d[nt * 16 + n];
            #pragma unroll
            for (int r = 0; r < 4; ++r) {
                const int row = r0 + r;
                const float v = acc[nt][r];
                float s = v * as;
                float d = v * ad;
                #pragma unroll
                for (int off = 8; off; off >>= 1) {
                    s += __shfl_xor(s, off, 16);
                    d += __shfl_xor(d, off, 16);
                }
                if (row < N_NODES) {
                    xlh[(size_t)row * DIM + nt * 16 + n] = __float2half(v);
                    if (n == 0) {
                        // fold 1/ln2 into the attention logits so the edge
                        // kernel can use a bare exp2 (leaky-relu commutes
                        // with positive scaling).
                        a_src[row * HEADS + nt] = s * 1.44269504f;
                        a_dst[row * HEADS + nt] = d * 1.44269504f;
                    }
                }
            }
        }
    }
}

// ---------------------------------------------------------------------------
// K2 (binB2): one block per bucket.
//  (a) LDS-scan bcur[196] -> this bucket's global edge offset boff.
//  (b) LDS-scan its 256 deg values -> exact per-node starts; write nrange;
//      init LDS cursors.
//  (c) scatter the bucket's pairs: pos = LDS atomicAdd(cur[dst&255]);
//      csr[pos] = src. 2B stores land in the bucket's own contiguous
//      ~16 KB csr window (single-CU-owned L2 lines). No global atomics.
// Block 0 threads also zero the BN accumulators.
// ---------------------------------------------------------------------------
__global__ __launch_bounds__(512) void k_binB2(const unsigned int* __restrict__ pairs,
                                               const int* __restrict__ bcur,
                                               const int* __restrict__ deg,
                                               unsigned short* __restrict__ csr,
                                               int2* __restrict__ nrange,
                                               float* __restrict__ gsums) {
    __shared__ int bsc[256];   // bucket-count inclusive scan
    __shared__ int dsc[256];   // per-node inclusive scan
    __shared__ int cur[256];   // per-node write cursors (global csr indices)
    const int t = threadIdx.x;
    const int b = blockIdx.x;
    if (b == 0 && t < 256) gsums[t] = 0.f;   // used by k_stats later

    // (a) bucket offset
    if (t < 256) bsc[t] = (t < NBUCK) ? bcur[t] : 0;
    __syncthreads();
    for (int d = 1; d < 256; d <<= 1) {
        int xo = 0;
        if (t < 256 && t >= d) xo = bsc[t - d];
        __syncthreads();
        if (t < 256) bsc[t] += xo;
        __syncthreads();
    }
    const int boff = (b == 0) ? 0 : bsc[b - 1];

    // (b) per-node starts
    int dg = 0;
    const int node = (b << 8) + t;
    if (t < 256) {
        dg = (node < N_NODES) ? deg[node] : 0;
        dsc[t] = dg;
    }
    __syncthreads();
    for (int d = 1; d < 256; d <<= 1) {
        int xo = 0;
        if (t < 256 && t >= d) xo = dsc[t - d];
        __syncthreads();
        if (t < 256) dsc[t] += xo;
        __syncthreads();
    }
    if (t < 256) {
        const int start = boff + dsc[t] - dg;
        if (node < N_NODES) {
            int2 rg; rg.x = start; rg.y = start + dg;
            nrange[node] = rg;
        }
        cur[t] = start;
    }
    __syncthreads();

    // (c) scatter
    const int cnt = bcur[b];
    const int lo = b * SEGCAP;
    for (int i = t; i < cnt; i += 512) {
        const unsigned int u = pairs[lo + i];
        const int dl = (u >> 16) & 255;
        const int pos = atomicAdd(&cur[dl], 1);
        csr[pos] = (unsigned short)(u & 0xFFFF);
    }
}

// ---------------------------------------------------------------------------
// K3 v9 (unchanged, proven 61 µs): fused softmax + aggregation. One node per
// wave, 4 edge-groups x 16 lanes, lane covers 8 channels via one f16x8
// gather; 16-edge main loop (4 independent dependent-chains in flight).
// Logits pre-scaled by 1/ln2 -> bare exp2f. Butterfly (xor 16,32) recombine;
// coalesced float2 full-row write.
// ---------------------------------------------------------------------------
#define AGG_NB (N_NODES / 4)   // 12500

__global__ void k_aggr9(const int2* __restrict__ nrange,
                        const unsigned short* __restrict__ csr,
                        const float* __restrict__ a_src, const float* __restrict__ a_dst,
                        const __half* __restrict__ xlh, float* __restrict__ y) {
    const int d = blockIdx.x * 4 + (threadIdx.x >> 6);
    const int lane = threadIdx.x & 63;
    const int g = lane >> 4;        // edge sub-group 0..3
    const int cl = lane & 15;       // channel slot: channels [cl*8, cl*8+8)
    const int h = cl >> 1;          // head owning this slot (OUT_C=16)
    const int2 rg = nrange[d];
    const int lo = rg.x, hi = rg.y;
    const float ad = a_dst[d * HEADS + h];

    float acc[8];
    #pragma unroll
    for (int k = 0; k < 8; ++k) acc[k] = 0.f;
    float dsum = 0.f;

    int i = lo;
    // 16 edges per iteration: 4 independent 4-edge batches
    for (; i + 16 <= hi; i += 16) {
        const int s0 = csr[i + g];
        const int s1 = csr[i + 4 + g];
        const int s2 = csr[i + 8 + g];
        const int s3 = csr[i + 12 + g];
        const float as0 = a_src[s0 * HEADS + h];
        const float as1 = a_src[s1 * HEADS + h];
        const float as2 = a_src[s2 * HEADS + h];
        const float as3 = a_src[s3 * HEADS + h];
        const f16x8 x0 = *(const f16x8*)(xlh + (size_t)s0 * DIM + cl * 8);
        const f16x8 x1 = *(const f16x8*)(xlh + (size_t)s1 * DIM + cl * 8);
        const f16x8 x2 = *(const f16x8*)(xlh + (size_t)s2 * DIM + cl * 8);
        const f16x8 x3 = *(const f16x8*)(xlh + (size_t)s3 * DIM + cl * 8);
        const float e0 = as0 + ad;
        const float e1 = as1 + ad;
        const float e2 = as2 + ad;
        const float e3 = as3 + ad;
        const float w0 = exp2f(fmaxf(e0, NEG_SLOPE * e0));
        const float w1 = exp2f(fmaxf(e1, NEG_SLOPE * e1));
        const float w2 = exp2f(fmaxf(e2, NEG_SLOPE * e2));
        const float w3 = exp2f(fmaxf(e3, NEG_SLOPE * e3));
        dsum += (w0 + w1) + (w2 + w3);
        #pragma unroll
        for (int k = 0; k < 8; ++k) acc[k] = fmaf(w0, (float)x0[k], acc[k]);
        #pragma unroll
        for (int k = 0; k < 8; ++k) acc[k] = fmaf(w1, (float)x1[k], acc[k]);
        #pragma unroll
        for (int k = 0; k < 8; ++k) acc[k] = fmaf(w2, (float)x2[k], acc[k]);
        #pragma unroll
        for (int k = 0; k < 8; ++k) acc[k] = fmaf(w3, (float)x3[k], acc[k]);
    }
    for (; i + 8 <= hi; i += 8) {
        const int s0 = csr[i + g];
        const int s1 = csr[i + 4 + g];
        const float as0 = a_src[s0 * HEADS + h];
        const float as1 = a_src[s1 * HEADS + h];
        const f16x8 x0 = *(const f16x8*)(xlh + (size_t)s0 * DIM + cl * 8);
        const f16x8 x1 = *(const f16x8*)(xlh + (size_t)s1 * DIM + cl * 8);
        const float e0 = as0 + ad;
        const float e1 = as1 + ad;
        const float w0 = exp2f(fmaxf(e0, NEG_SLOPE * e0));
        const float w1 = exp2f(fmaxf(e1, NEG_SLOPE * e1));
        dsum += w0 + w1;
        #pragma unroll
        for (int k = 0; k < 8; ++k) acc[k] = fmaf(w0, (float)x0[k], acc[k]);
        #pragma unroll
        for (int k = 0; k < 8; ++k) acc[k] = fmaf(w1, (float)x1[k], acc[k]);
    }
    // tail: up to 7 edges, predicated per group (loop bounds wave-uniform)
    for (; i < hi; i += 4) {
        const int idx = i + g;
        const int sv = csr[min(idx, hi - 1)];
        const float e = a_src[sv * HEADS + h] + ad;
        const f16x8 xv = *(const f16x8*)(xlh + (size_t)sv * DIM + cl * 8);
        float w = exp2f(fmaxf(e, NEG_SLOPE * e));
        if (idx >= hi) w = 0.f;
        dsum += w;
        #pragma unroll
        for (int k = 0; k < 8; ++k) acc[k] = fmaf(w, (float)xv[k], acc[k]);
    }
    // cross-group reduce: lanes {l, l^16, l^32, l^48} share channel slot cl
    #pragma unroll
    for (int k = 0; k < 8; ++k) {
        acc[k] += __shfl_xor(acc[k], 16);
        acc[k] += __shfl_xor(acc[k], 32);
    }
    dsum += __shfl_xor(dsum, 16);
    dsum += __shfl_xor(dsum, 32);
    const float inv = 1.f / (dsum + 1e-16f);
    float2 o;
    o.x = acc[2 * g] * inv;
    o.y = acc[2 * g + 1] * inv;
    // lane writes channels cl*8 + 2g, +1: 64 distinct float2 = full row
    *(float2*)(y + (size_t)d * DIM + cl * 8 + g * 2) = o;
}

// ---------------------------------------------------------------------------
// BN stats over h = y + bias (512 blocks x 128 threads)
// ---------------------------------------------------------------------------
__global__ void k_stats(const float* __restrict__ y, const float* __restrict__ bias,
                        float* __restrict__ gsums) {
    const int c = threadIdx.x;
    const float b = bias[c];
    float s = 0.f, ss = 0.f;
    for (int n = blockIdx.x; n < N_NODES; n += gridDim.x) {
        const float h = y[n * DIM + c] + b;
        s += h;
        ss += h * h;
    }
    atomicAdd(&gsums[c], s);
    atomicAdd(&gsums[DIM + c], ss);
}

// ---------------------------------------------------------------------------
// K4: y = x + relu((y + bias - mean) * rsqrt(var+eps) * gamma + beta)
// BN fold computed inline per thread (sums/sumsq L2-resident).
// ---------------------------------------------------------------------------
__global__ void k_final(float* __restrict__ y, const float* __restrict__ x,
                        const float* __restrict__ sums, const float* __restrict__ sumsq,
                        const float* __restrict__ gamma, const float* __restrict__ beta,
                        const float* __restrict__ bias) {
    const int q = blockIdx.x * blockDim.x + threadIdx.x;
    const int cq = q & (DIM / 4 - 1);
    const float4 sm = ((const float4*)sums)[cq];
    const float4 sq = ((const float4*)sumsq)[cq];
    const float4 gm = ((const float4*)gamma)[cq];
    const float4 bt = ((const float4*)beta)[cq];
    const float4 bs = ((const float4*)bias)[cq];
    float4 v = ((const float4*)y)[q];
    const float4 xv = ((const float4*)x)[q];
    const float inv_n = 1.f / (float)N_NODES;
#define BNC(c) { const float mean = sm.c * inv_n;                         \
                 const float var = sq.c * inv_n - mean * mean;            \
                 const float sc = rsqrtf(var + BN_EPS) * gm.c;            \
                 const float sh = bt.c + (bs.c - mean) * sc;              \
                 v.c = xv.c + fmaxf(v.c * sc + sh, 0.f); }
    BNC(x) BNC(y) BNC(z) BNC(w)
#undef BNC
    ((float4*)y)[q] = v;
}

extern "C" void kernel_launch(void* const* d_in, const int* in_sizes, int n_in,
                              void* d_out, int out_size, void* d_ws, size_t ws_size,
                              hipStream_t stream) {
    const float* x     = (const float*)d_in[0];
    const int*   ei    = (const int*)  d_in[1];
    const float* W     = (const float*)d_in[2];
    const float* att_s = (const float*)d_in[3];
    const float* att_d = (const float*)d_in[4];
    const float* bias  = (const float*)d_in[5];
    const float* gamma = (const float*)d_in[6];
    const float* beta  = (const float*)d_in[7];
    float* y = (float*)d_out;

    // workspace layout (~25.8 MiB total)
    __half* xlh  = (__half*)d_ws;                          // 12.8 MB
    float* a_src = (float*)(xlh + (size_t)N_NODES * DIM);  // 1.6 MB
    float* a_dst = a_src + (size_t)N_NODES * HEADS;        // 1.6 MB
    float* sums  = a_dst + (size_t)N_NODES * HEADS;        // 512 B
    float* sumsq = sums  + DIM;                            // 512 B
    int*   deg   = (int*)(sumsq + DIM);                    // 200 KB
    int*   bcur  = deg + N_NODES;                          // 1 KB
    int2*  nrange = (int2*)(bcur + 256);                   // 400 KB
    unsigned int* pairs = (unsigned int*)(nrange + N_NODES); // 196*9216 u32 (7.2 MB)
    unsigned short* csr = (unsigned short*)(pairs + (size_t)NBUCK * SEGCAP); // 3.2 MB

    // zero sums/sumsq + deg + bcur in one contiguous memset
    hipMemsetAsync(sums, 0, (size_t)(2 * DIM + N_NODES + 256) * sizeof(int), stream);
    k_linbinA<<<FUSED_NB, 512, 0, stream>>>(x, W, att_s, att_d, ei, bcur, deg,
                                            pairs, xlh, a_src, a_dst);
    k_binB2<<<NBUCK, 512, 0, stream>>>(pairs, bcur, deg, csr, nrange, sums);
    k_aggr9<<<AGG_NB, 256, 0, stream>>>(nrange, csr, a_src, a_dst, xlh, y);
    k_stats<<<512, DIM, 0, stream>>>(y, bias, sums);
    k_final<<<(size_t)N_NODES * DIM / 4 / 256, 256, 0, stream>>>(y, x, sums, sumsq,
                                                                 gamma, beta, bias);
}

// Round 6
// 241.072 us; speedup vs baseline: 1.9486x; 1.1978x over previous
//
#include <hip/hip_runtime.h>
#include <hip/hip_fp16.h>
#include <math.h>

#define N_NODES 50000
#define N_EDGES 1600000
#define DIM 128
#define HEADS 8
#define NEG_SLOPE 0.2f
#define BN_EPS 1e-5f

typedef _Float16 f16x8 __attribute__((ext_vector_type(8)));
typedef float f32x4 __attribute__((ext_vector_type(4)));

// ---------------------------------------------------------------------------
// CSR build: bucket b = dst>>8 (196 buckets of 256 nodes).
// Phase A: chunk-block sorts its 8192 edges by bucket into its OWN pairs
//   region (block-major) and publishes per-bucket {len,off} metadata.
//   -> NO global atomics anywhere in the build (R5 lesson: returning
//      cross-XCD atomics on hot counters serialize ~200 blocks).
// Phase B: bucket-block gathers its runs via metadata + LDS binary search,
//   LDS-sorts by node, flushes to csr segment b*SEGCAP.
// Both phases are co-packed with lin blocks so no phase runs half-idle.
// ---------------------------------------------------------------------------
#define NBUCK 196
#define SEGCAP 12288
#define CHUNK 8192
#define NB_A ((N_EDGES + CHUNK - 1) / CHUNK)   // 196
#define LIN_NB ((N_NODES + 127) / 128)          // 391 (8 waves x 16 nodes)
#define LIN_K1 195
#define LIN_K2 (LIN_NB - LIN_K1)                // 196
#define P1_NB (NB_A + LIN_K1)                   // 391
#define P2_NB (NBUCK + LIN_K2)                  // 392

struct BinAShm {
    int hist[NBUCK], excl[NBUCK], cnt2[NBUCK];
    int sc[256];
    unsigned int buf[CHUNK];                // 32 KB
};
struct BinBShm {
    int la[256], ea[256], rs[256];          // run len / run off / incl scan
    int hist[256], excl[256], cnt2[256], sc[256];
    unsigned short out[SEGCAP];             // 24 KB
};
struct LinShm { __half wh[16384]; };        // 32 KB

// ---------------------------------------------------------------------------
// lin: xl = x @ W via MFMA 16x16x32 f16, W swizzled fp32->fp16 in LDS;
// fused per-head attention dots, logits pre-scaled by 1/ln2 (exp2 later).
// ---------------------------------------------------------------------------
__device__ __forceinline__ void lin_block(
        int linb, const float* __restrict__ x, const float* __restrict__ W,
        const float* __restrict__ att_s, const float* __restrict__ att_d,
        __half* __restrict__ xlh, float* __restrict__ a_src,
        float* __restrict__ a_dst, __half* wh) {
    const int t = threadIdx.x;
    // stage W: frag g=nt*4+kt: lane holds B[k=kt*32+q*8+j][n=nt*16+(lane&15)]
    for (int v = t; v < 2048; v += 512) {
        const int g = v >> 6, lane = v & 63;
        const int nt = g >> 2, kt = g & 3;
        const int q = lane >> 4, n = lane & 15;
        #pragma unroll
        for (int j = 0; j < 8; ++j)
            wh[(size_t)(g * 64 + lane) * 8 + j] =
                __float2half(W[(kt * 32 + q * 8 + j) * DIM + nt * 16 + n]);
    }
    __syncthreads();

    const int wave = t >> 6;
    const int lane = t & 63;
    const int q = lane >> 4, n = lane & 15;
    const int nb = (linb * 8 + wave) * 16;

    const int rowA = min(nb + n, N_NODES - 1);
    const float* xr = x + (size_t)rowA * DIM;
    f16x8 a[4];
    #pragma unroll
    for (int kt = 0; kt < 4; ++kt) {
        const float4 p0 = *(const float4*)(xr + kt * 32 + q * 8);
        const float4 p1 = *(const float4*)(xr + kt * 32 + q * 8 + 4);
        a[kt][0] = (_Float16)p0.x; a[kt][1] = (_Float16)p0.y;
        a[kt][2] = (_Float16)p0.z; a[kt][3] = (_Float16)p0.w;
        a[kt][4] = (_Float16)p1.x; a[kt][5] = (_Float16)p1.y;
        a[kt][6] = (_Float16)p1.z; a[kt][7] = (_Float16)p1.w;
    }

    f32x4 acc[8];
    #pragma unroll
    for (int nt = 0; nt < 8; ++nt) acc[nt] = (f32x4){0.f, 0.f, 0.f, 0.f};

    const f16x8* wb = (const f16x8*)wh;
    #pragma unroll
    for (int nt = 0; nt < 8; ++nt) {
        #pragma unroll
        for (int kt = 0; kt < 4; ++kt) {
            const f16x8 b = wb[(nt * 4 + kt) * 64 + lane];
            acc[nt] = __builtin_amdgcn_mfma_f32_16x16x32_f16(a[kt], b, acc[nt], 0, 0, 0);
        }
    }

    const int r0 = nb + q * 4;
    #pragma unroll
    for (int nt = 0; nt < 8; ++nt) {
        const float as = att_s[nt * 16 + n];
        const float ad = att_d[nt * 16 + n];
        #pragma unroll
        for (int r = 0; r < 4; ++r) {
            const int row = r0 + r;
            const float v = acc[nt][r];
            float s = v * as;
            float d = v * ad;
            #pragma unroll
            for (int off = 8; off; off >>= 1) {
                s += __shfl_xor(s, off, 16);
                d += __shfl_xor(d, off, 16);
            }
            if (row < N_NODES) {
                xlh[(size_t)row * DIM + nt * 16 + n] = __float2half(v);
                if (n == 0) {
                    a_src[row * HEADS + nt] = s * 1.44269504f;
                    a_dst[row * HEADS + nt] = d * 1.44269504f;
                }
            }
        }
    }
}

// ---------------------------------------------------------------------------
// K1: blocks [0, NB_A) = binA; blocks [NB_A, P1_NB) = lin part 1.
// ---------------------------------------------------------------------------
__global__ __launch_bounds__(512) void k_phase1(
        const float* __restrict__ x, const float* __restrict__ W,
        const float* __restrict__ att_s, const float* __restrict__ att_d,
        const int* __restrict__ ei, unsigned int* __restrict__ meta,
        unsigned int* __restrict__ pairs, __half* __restrict__ xlh,
        float* __restrict__ a_src, float* __restrict__ a_dst) {
    __shared__ union { BinAShm a; LinShm l; } sh;
    const int t = threadIdx.x;

    if (blockIdx.x < NB_A) {
        // ----- binA: LDS counting sort of one 8192-edge chunk by bucket -----
        const int blk = blockIdx.x;
        const int base = blk * CHUNK;
        const int cnt = min(CHUNK, N_EDGES - base);   // multiple of 4

        if (t < NBUCK) { sh.a.hist[t] = 0; sh.a.cnt2[t] = 0; }
        __syncthreads();
        for (int i = t * 4; i < cnt; i += 2048) {
            const int4 dv = *(const int4*)(ei + N_EDGES + base + i);
            atomicAdd(&sh.a.hist[dv.x >> 8], 1);
            atomicAdd(&sh.a.hist[dv.y >> 8], 1);
            atomicAdd(&sh.a.hist[dv.z >> 8], 1);
            atomicAdd(&sh.a.hist[dv.w >> 8], 1);
        }
        __syncthreads();
        if (t < 256) sh.a.sc[t] = (t < NBUCK) ? sh.a.hist[t] : 0;
        __syncthreads();
        for (int d = 1; d < 256; d <<= 1) {
            int xo = 0;
            if (t < 256 && t >= d) xo = sh.a.sc[t - d];
            __syncthreads();
            if (t < 256) sh.a.sc[t] += xo;
            __syncthreads();
        }
        if (t < NBUCK) {
            const int ex = sh.a.sc[t] - sh.a.hist[t];
            sh.a.excl[t] = ex;
            // publish {len, off} for this (chunk, bucket): no global atomics
            meta[(size_t)blk * NBUCK + t] =
                (unsigned int)sh.a.hist[t] | ((unsigned int)ex << 16);
        }
        __syncthreads();
        for (int i = t * 4; i < cnt; i += 2048) {
            const int4 sv = *(const int4*)(ei + base + i);
            const int4 dv = *(const int4*)(ei + N_EDGES + base + i);
            const int ss[4] = {sv.x, sv.y, sv.z, sv.w};
            const int dd[4] = {dv.x, dv.y, dv.z, dv.w};
            #pragma unroll
            for (int k = 0; k < 4; ++k) {
                const int b = dd[k] >> 8;
                const int r = atomicAdd(&sh.a.cnt2[b], 1);
                sh.a.buf[sh.a.excl[b] + r] = (unsigned int)ss[k]
                    | ((unsigned int)(dd[k] & 255) << 16);
            }
        }
        __syncthreads();
        // coalesced flush into this block's OWN region
        for (int i = t * 4; i < cnt; i += 2048)
            *(int4*)(pairs + base + i) = *(const int4*)(sh.a.buf + i);
    } else {
        lin_block(blockIdx.x - NB_A, x, W, att_s, att_d, xlh, a_src, a_dst, sh.l.wh);
    }
}

// ---------------------------------------------------------------------------
// K2: blocks [0, NBUCK) = binB; blocks [NBUCK, P2_NB) = lin part 2.
// binB: gather bucket edges from 196 metadata runs (8-step LDS bsearch per
// edge), LDS histogram -> scan -> scatter by node, flush to csr segment.
// Block 0 zeroes BN accumulators.
// ---------------------------------------------------------------------------
__global__ __launch_bounds__(512) void k_phase2(
        const unsigned int* __restrict__ pairs, const unsigned int* __restrict__ meta,
        unsigned short* __restrict__ csr, int2* __restrict__ nrange,
        float* __restrict__ gsums,
        const float* __restrict__ x, const float* __restrict__ W,
        const float* __restrict__ att_s, const float* __restrict__ att_d,
        __half* __restrict__ xlh, float* __restrict__ a_src,
        float* __restrict__ a_dst) {
    __shared__ union { BinBShm b; LinShm l; } sh;
    const int t = threadIdx.x;

    if (blockIdx.x < NBUCK) {
        const int b = blockIdx.x;
        if (b == 0 && t < 256) gsums[t] = 0.f;

        // meta column: run lengths/offsets of bucket b in every chunk
        if (t < 256) {
            int len = 0, off = 0;
            if (t < NB_A) {
                const unsigned int m = meta[(size_t)t * NBUCK + b];
                len = (int)(m & 0xFFFF);
                off = (int)(m >> 16);
            }
            sh.b.la[t] = len; sh.b.ea[t] = off; sh.b.rs[t] = len;
            sh.b.hist[t] = 0; sh.b.cnt2[t] = 0;
        }
        __syncthreads();
        // inclusive scan of run lengths
        for (int d = 1; d < 256; d <<= 1) {
            int xo = 0;
            if (t < 256 && t >= d) xo = sh.b.rs[t - d];
            __syncthreads();
            if (t < 256) sh.b.rs[t] += xo;
            __syncthreads();
        }
        const int cnt = sh.b.rs[NB_A - 1];

        // pass 1: per-node histogram
        for (int i = t; i < cnt; i += 512) {
            int loa = 0, hia = NB_A - 1;
            while (loa < hia) {
                const int mid = (loa + hia) >> 1;
                if (sh.b.rs[mid] > i) hia = mid; else loa = mid + 1;
            }
            const int j = i - (sh.b.rs[loa] - sh.b.la[loa]);
            const unsigned int u = pairs[(size_t)loa * CHUNK + sh.b.ea[loa] + j];
            atomicAdd(&sh.b.hist[(u >> 16) & 255], 1);
        }
        __syncthreads();
        if (t < 256) sh.b.sc[t] = sh.b.hist[t];
        __syncthreads();
        for (int d = 1; d < 256; d <<= 1) {
            int xo = 0;
            if (t < 256 && t >= d) xo = sh.b.sc[t - d];
            __syncthreads();
            if (t < 256) sh.b.sc[t] += xo;
            __syncthreads();
        }
        if (t < 256) sh.b.excl[t] = sh.b.sc[t] - sh.b.hist[t];
        __syncthreads();

        // pass 2: scatter into node-sorted LDS staging
        for (int i = t; i < cnt; i += 512) {
            int loa = 0, hia = NB_A - 1;
            while (loa < hia) {
                const int mid = (loa + hia) >> 1;
                if (sh.b.rs[mid] > i) hia = mid; else loa = mid + 1;
            }
            const int j = i - (sh.b.rs[loa] - sh.b.la[loa]);
            const unsigned int u = pairs[(size_t)loa * CHUNK + sh.b.ea[loa] + j];
            const int dl = (u >> 16) & 255;
            const int r = atomicAdd(&sh.b.cnt2[dl], 1);
            sh.b.out[sh.b.excl[dl] + r] = (unsigned short)(u & 0xFFFF);
        }
        __syncthreads();
        // coalesced flush + node ranges
        for (int i = t; i < cnt; i += 512)
            csr[(size_t)b * SEGCAP + i] = sh.b.out[i];
        if (t < 256) {
            const int node = (b << 8) + t;
            if (node < N_NODES) {
                int2 rg;
                rg.x = b * SEGCAP + sh.b.excl[t];
                rg.y = rg.x + sh.b.hist[t];
                nrange[node] = rg;
            }
        }
    } else {
        lin_block(LIN_K1 + (int)blockIdx.x - NBUCK, x, W, att_s, att_d,
                  xlh, a_src, a_dst, sh.l.wh);
    }
}

// ---------------------------------------------------------------------------
// K3 v9 (unchanged, proven 61 µs): fused softmax + aggregation. One node per
// wave, 4 edge-groups x 16 lanes, lane covers 8 channels via one f16x8
// gather; 16-edge main loop. Logits pre-scaled by 1/ln2 -> bare exp2f.
// ---------------------------------------------------------------------------
#define AGG_NB (N_NODES / 4)   // 12500

__global__ void k_aggr9(const int2* __restrict__ nrange,
                        const unsigned short* __restrict__ csr,
                        const float* __restrict__ a_src, const float* __restrict__ a_dst,
                        const __half* __restrict__ xlh, float* __restrict__ y) {
    const int d = blockIdx.x * 4 + (threadIdx.x >> 6);
    const int lane = threadIdx.x & 63;
    const int g = lane >> 4;        // edge sub-group 0..3
    const int cl = lane & 15;       // channel slot: channels [cl*8, cl*8+8)
    const int h = cl >> 1;          // head owning this slot (OUT_C=16)
    const int2 rg = nrange[d];
    const int lo = rg.x, hi = rg.y;
    const float ad = a_dst[d * HEADS + h];

    float acc[8];
    #pragma unroll
    for (int k = 0; k < 8; ++k) acc[k] = 0.f;
    float dsum = 0.f;

    int i = lo;
    for (; i + 16 <= hi; i += 16) {
        const int s0 = csr[i + g];
        const int s1 = csr[i + 4 + g];
        const int s2 = csr[i + 8 + g];
        const int s3 = csr[i + 12 + g];
        const float as0 = a_src[s0 * HEADS + h];
        const float as1 = a_src[s1 * HEADS + h];
        const float as2 = a_src[s2 * HEADS + h];
        const float as3 = a_src[s3 * HEADS + h];
        const f16x8 x0 = *(const f16x8*)(xlh + (size_t)s0 * DIM + cl * 8);
        const f16x8 x1 = *(const f16x8*)(xlh + (size_t)s1 * DIM + cl * 8);
        const f16x8 x2 = *(const f16x8*)(xlh + (size_t)s2 * DIM + cl * 8);
        const f16x8 x3 = *(const f16x8*)(xlh + (size_t)s3 * DIM + cl * 8);
        const float e0 = as0 + ad;
        const float e1 = as1 + ad;
        const float e2 = as2 + ad;
        const float e3 = as3 + ad;
        const float w0 = exp2f(fmaxf(e0, NEG_SLOPE * e0));
        const float w1 = exp2f(fmaxf(e1, NEG_SLOPE * e1));
        const float w2 = exp2f(fmaxf(e2, NEG_SLOPE * e2));
        const float w3 = exp2f(fmaxf(e3, NEG_SLOPE * e3));
        dsum += (w0 + w1) + (w2 + w3);
        #pragma unroll
        for (int k = 0; k < 8; ++k) acc[k] = fmaf(w0, (float)x0[k], acc[k]);
        #pragma unroll
        for (int k = 0; k < 8; ++k) acc[k] = fmaf(w1, (float)x1[k], acc[k]);
        #pragma unroll
        for (int k = 0; k < 8; ++k) acc[k] = fmaf(w2, (float)x2[k], acc[k]);
        #pragma unroll
        for (int k = 0; k < 8; ++k) acc[k] = fmaf(w3, (float)x3[k], acc[k]);
    }
    for (; i + 8 <= hi; i += 8) {
        const int s0 = csr[i + g];
        const int s1 = csr[i + 4 + g];
        const float as0 = a_src[s0 * HEADS + h];
        const float as1 = a_src[s1 * HEADS + h];
        const f16x8 x0 = *(const f16x8*)(xlh + (size_t)s0 * DIM + cl * 8);
        const f16x8 x1 = *(const f16x8*)(xlh + (size_t)s1 * DIM + cl * 8);
        const float e0 = as0 + ad;
        const float e1 = as1 + ad;
        const float w0 = exp2f(fmaxf(e0, NEG_SLOPE * e0));
        const float w1 = exp2f(fmaxf(e1, NEG_SLOPE * e1));
        dsum += w0 + w1;
        #pragma unroll
        for (int k = 0; k < 8; ++k) acc[k] = fmaf(w0, (float)x0[k], acc[k]);
        #pragma unroll
        for (int k = 0; k < 8; ++k) acc[k] = fmaf(w1, (float)x1[k], acc[k]);
    }
    for (; i < hi; i += 4) {
        const int idx = i + g;
        const int sv = csr[min(idx, hi - 1)];
        const float e = a_src[sv * HEADS + h] + ad;
        const f16x8 xv = *(const f16x8*)(xlh + (size_t)sv * DIM + cl * 8);
        float w = exp2f(fmaxf(e, NEG_SLOPE * e));
        if (idx >= hi) w = 0.f;
        dsum += w;
        #pragma unroll
        for (int k = 0; k < 8; ++k) acc[k] = fmaf(w, (float)xv[k], acc[k]);
    }
    #pragma unroll
    for (int k = 0; k < 8; ++k) {
        acc[k] += __shfl_xor(acc[k], 16);
        acc[k] += __shfl_xor(acc[k], 32);
    }
    dsum += __shfl_xor(dsum, 16);
    dsum += __shfl_xor(dsum, 32);
    const float inv = 1.f / (dsum + 1e-16f);
    float2 o;
    o.x = acc[2 * g] * inv;
    o.y = acc[2 * g + 1] * inv;
    *(float2*)(y + (size_t)d * DIM + cl * 8 + g * 2) = o;
}

// ---------------------------------------------------------------------------
// BN stats over h = y + bias (512 blocks x 128 threads)
// ---------------------------------------------------------------------------
__global__ void k_stats(const float* __restrict__ y, const float* __restrict__ bias,
                        float* __restrict__ gsums) {
    const int c = threadIdx.x;
    const float b = bias[c];
    float s = 0.f, ss = 0.f;
    for (int n = blockIdx.x; n < N_NODES; n += gridDim.x) {
        const float h = y[n * DIM + c] + b;
        s += h;
        ss += h * h;
    }
    atomicAdd(&gsums[c], s);
    atomicAdd(&gsums[DIM + c], ss);
}

// ---------------------------------------------------------------------------
// K4: y = x + relu((y + bias - mean) * rsqrt(var+eps) * gamma + beta)
// ---------------------------------------------------------------------------
__global__ void k_final(float* __restrict__ y, const float* __restrict__ x,
                        const float* __restrict__ sums, const float* __restrict__ sumsq,
                        const float* __restrict__ gamma, const float* __restrict__ beta,
                        const float* __restrict__ bias) {
    const int q = blockIdx.x * blockDim.x + threadIdx.x;
    const int cq = q & (DIM / 4 - 1);
    const float4 sm = ((const float4*)sums)[cq];
    const float4 sq = ((const float4*)sumsq)[cq];
    const float4 gm = ((const float4*)gamma)[cq];
    const float4 bt = ((const float4*)beta)[cq];
    const float4 bs = ((const float4*)bias)[cq];
    float4 v = ((const float4*)y)[q];
    const float4 xv = ((const float4*)x)[q];
    const float inv_n = 1.f / (float)N_NODES;
#define BNC(c) { const float mean = sm.c * inv_n;                         \
                 const float var = sq.c * inv_n - mean * mean;            \
                 const float sc = rsqrtf(var + BN_EPS) * gm.c;            \
                 const float sh = bt.c + (bs.c - mean) * sc;              \
                 v.c = xv.c + fmaxf(v.c * sc + sh, 0.f); }
    BNC(x) BNC(y) BNC(z) BNC(w)
#undef BNC
    ((float4*)y)[q] = v;
}

extern "C" void kernel_launch(void* const* d_in, const int* in_sizes, int n_in,
                              void* d_out, int out_size, void* d_ws, size_t ws_size,
                              hipStream_t stream) {
    const float* x     = (const float*)d_in[0];
    const int*   ei    = (const int*)  d_in[1];
    const float* W     = (const float*)d_in[2];
    const float* att_s = (const float*)d_in[3];
    const float* att_d = (const float*)d_in[4];
    const float* bias  = (const float*)d_in[5];
    const float* gamma = (const float*)d_in[6];
    const float* beta  = (const float*)d_in[7];
    float* y = (float*)d_out;

    // workspace layout (~27.8 MiB)
    __half* xlh  = (__half*)d_ws;                          // 12.8 MB
    float* a_src = (float*)(xlh + (size_t)N_NODES * DIM);  // 1.6 MB
    float* a_dst = a_src + (size_t)N_NODES * HEADS;        // 1.6 MB
    float* sums  = a_dst + (size_t)N_NODES * HEADS;        // 512 B
    float* sumsq = sums  + DIM;                            // 512 B
    int2*  nrange = (int2*)(sumsq + DIM);                  // 400 KB
    unsigned int* meta  = (unsigned int*)(nrange + N_NODES);   // 196*196 u32 (154 KB)
    unsigned int* pairs = meta + (size_t)NB_A * NBUCK;         // 196*8192 u32 (6.4 MB)
    unsigned short* csr = (unsigned short*)(pairs + (size_t)NB_A * CHUNK); // 4.8 MB

    k_phase1<<<P1_NB, 512, 0, stream>>>(x, W, att_s, att_d, ei, meta, pairs,
                                        xlh, a_src, a_dst);
    k_phase2<<<P2_NB, 512, 0, stream>>>(pairs, meta, csr, nrange, sums,
                                        x, W, att_s, att_d, xlh, a_src, a_dst);
    k_aggr9<<<AGG_NB, 256, 0, stream>>>(nrange, csr, a_src, a_dst, xlh, y);
    k_stats<<<512, DIM, 0, stream>>>(y, bias, sums);
    k_final<<<(size_t)N_NODES * DIM / 4 / 256, 256, 0, stream>>>(y, x, sums, sumsq,
                                                                 gamma, beta, bias);
}

// Round 9
// 234.094 us; speedup vs baseline: 2.0066x; 1.0298x over previous
//
#include <hip/hip_runtime.h>
#include <hip/hip_fp16.h>
#include <math.h>

#define N_NODES 50000
#define N_EDGES 1600000
#define DIM 128
#define HEADS 8
#define NEG_SLOPE 0.2f
#define BN_EPS 1e-5f

typedef _Float16 f16x8 __attribute__((ext_vector_type(8)));
typedef float f32x4 __attribute__((ext_vector_type(4)));

// ---------------------------------------------------------------------------
// CSR build: bucket b = dst>>8 (196 buckets of 256 nodes).
// Phase A: chunk-block sorts its 8192 edges by bucket into its OWN pairs
//   region (block-major) and publishes per-bucket {len,off} metadata.
//   -> NO global atomics anywhere in the build.
// Phase B v3: bucket-block walks its 196 runs wave-cooperatively TWICE
//   (coalesced; pass1 histogram, pass2 scatter into LDS staging), then
//   coalesced flush. No binary search, no big LDS gather buffer.
// Both phases are co-packed with lin blocks so no phase runs half-idle.
// ---------------------------------------------------------------------------
#define NBUCK 196
#define SEGCAP 12288
#define CHUNK 8192
#define NB_A ((N_EDGES + CHUNK - 1) / CHUNK)   // 196
#define LIN_NB ((N_NODES + 127) / 128)          // 391 (8 waves x 16 nodes)
#define LIN_K1 195
#define LIN_K2 (LIN_NB - LIN_K1)                // 196
#define P1_NB (NB_A + LIN_K1)                   // 391
#define P2_NB (NBUCK + LIN_K2)                  // 392

struct BinAShm {
    int hist[NBUCK], excl[NBUCK], cnt2[NBUCK];
    int sc[256];
    unsigned int buf[CHUNK];                // 32 KB
};
struct BinBShm {
    int la[256], ea[256];                   // run len / run off per chunk
    int hist[256], excl[256], cnt2[256], sc[256];
    unsigned short out[SEGCAP];             // 24 KB node-sorted staging
};
struct LinShm { __half wh[16384]; };        // 32 KB

// ---------------------------------------------------------------------------
// lin: xl = x @ W via MFMA 16x16x32 f16, W swizzled fp32->fp16 in LDS;
// fused per-head attention dots, logits pre-scaled by 1/ln2 (exp2 later).
// ---------------------------------------------------------------------------
__device__ __forceinline__ void lin_block(
        int linb, const float* __restrict__ x, const float* __restrict__ W,
        const float* __restrict__ att_s, const float* __restrict__ att_d,
        __half* __restrict__ xlh, float* __restrict__ a_src,
        float* __restrict__ a_dst, __half* wh) {
    const int t = threadIdx.x;
    // stage W: frag g=nt*4+kt: lane holds B[k=kt*32+q*8+j][n=nt*16+(lane&15)]
    for (int v = t; v < 2048; v += 512) {
        const int g = v >> 6, lane = v & 63;
        const int nt = g >> 2, kt = g & 3;
        const int q = lane >> 4, n = lane & 15;
        #pragma unroll
        for (int j = 0; j < 8; ++j)
            wh[(size_t)(g * 64 + lane) * 8 + j] =
                __float2half(W[(kt * 32 + q * 8 + j) * DIM + nt * 16 + n]);
    }
    __syncthreads();

    const int wave = t >> 6;
    const int lane = t & 63;
    const int q = lane >> 4, n = lane & 15;
    const int nb = (linb * 8 + wave) * 16;

    const int rowA = min(nb + n, N_NODES - 1);
    const float* xr = x + (size_t)rowA * DIM;
    f16x8 a[4];
    #pragma unroll
    for (int kt = 0; kt < 4; ++kt) {
        const float4 p0 = *(const float4*)(xr + kt * 32 + q * 8);
        const float4 p1 = *(const float4*)(xr + kt * 32 + q * 8 + 4);
        a[kt][0] = (_Float16)p0.x; a[kt][1] = (_Float16)p0.y;
        a[kt][2] = (_Float16)p0.z; a[kt][3] = (_Float16)p0.w;
        a[kt][4] = (_Float16)p1.x; a[kt][5] = (_Float16)p1.y;
        a[kt][6] = (_Float16)p1.z; a[kt][7] = (_Float16)p1.w;
    }

    f32x4 acc[8];
    #pragma unroll
    for (int nt = 0; nt < 8; ++nt) acc[nt] = (f32x4){0.f, 0.f, 0.f, 0.f};

    const f16x8* wb = (const f16x8*)wh;
    #pragma unroll
    for (int nt = 0; nt < 8; ++nt) {
        #pragma unroll
        for (int kt = 0; kt < 4; ++kt) {
            const f16x8 b = wb[(nt * 4 + kt) * 64 + lane];
            acc[nt] = __builtin_amdgcn_mfma_f32_16x16x32_f16(a[kt], b, acc[nt], 0, 0, 0);
        }
    }

    const int r0 = nb + q * 4;
    #pragma unroll
    for (int nt = 0; nt < 8; ++nt) {
        const float as = att_s[nt * 16 + n];
        const float ad = att_d[nt * 16 + n];
        #pragma unroll
        for (int r = 0; r < 4; ++r) {
            const int row = r0 + r;
            const float v = acc[nt][r];
            float s = v * as;
            float d = v * ad;
            #pragma unroll
            for (int off = 8; off; off >>= 1) {
                s += __shfl_xor(s, off, 16);
                d += __shfl_xor(d, off, 16);
            }
            if (row < N_NODES) {
                xlh[(size_t)row * DIM + nt * 16 + n] = __float2half(v);
                if (n == 0) {
                    a_src[row * HEADS + nt] = s * 1.44269504f;
                    a_dst[row * HEADS + nt] = d * 1.44269504f;
                }
            }
        }
    }
}

// ---------------------------------------------------------------------------
// K1: blocks [0, NB_A) = binA; blocks [NB_A, P1_NB) = lin part 1.
// ---------------------------------------------------------------------------
__global__ __launch_bounds__(512) void k_phase1(
        const float* __restrict__ x, const float* __restrict__ W,
        const float* __restrict__ att_s, const float* __restrict__ att_d,
        const int* __restrict__ ei, unsigned int* __restrict__ meta,
        unsigned int* __restrict__ pairs, __half* __restrict__ xlh,
        float* __restrict__ a_src, float* __restrict__ a_dst) {
    __shared__ union { BinAShm a; LinShm l; } sh;
    const int t = threadIdx.x;

    if (blockIdx.x < NB_A) {
        // ----- binA: LDS counting sort of one 8192-edge chunk by bucket -----
        const int blk = blockIdx.x;
        const int base = blk * CHUNK;
        const int cnt = min(CHUNK, N_EDGES - base);   // multiple of 4

        if (t < NBUCK) { sh.a.hist[t] = 0; sh.a.cnt2[t] = 0; }
        __syncthreads();
        for (int i = t * 4; i < cnt; i += 2048) {
            const int4 dv = *(const int4*)(ei + N_EDGES + base + i);
            atomicAdd(&sh.a.hist[dv.x >> 8], 1);
            atomicAdd(&sh.a.hist[dv.y >> 8], 1);
            atomicAdd(&sh.a.hist[dv.z >> 8], 1);
            atomicAdd(&sh.a.hist[dv.w >> 8], 1);
        }
        __syncthreads();
        if (t < 256) sh.a.sc[t] = (t < NBUCK) ? sh.a.hist[t] : 0;
        __syncthreads();
        for (int d = 1; d < 256; d <<= 1) {
            int xo = 0;
            if (t < 256 && t >= d) xo = sh.a.sc[t - d];
            __syncthreads();
            if (t < 256) sh.a.sc[t] += xo;
            __syncthreads();
        }
        if (t < NBUCK) {
            const int ex = sh.a.sc[t] - sh.a.hist[t];
            sh.a.excl[t] = ex;
            // publish {len, off} for this (chunk, bucket): no global atomics
            meta[(size_t)blk * NBUCK + t] =
                (unsigned int)sh.a.hist[t] | ((unsigned int)ex << 16);
        }
        __syncthreads();
        for (int i = t * 4; i < cnt; i += 2048) {
            const int4 sv = *(const int4*)(ei + base + i);
            const int4 dv = *(const int4*)(ei + N_EDGES + base + i);
            const int ss[4] = {sv.x, sv.y, sv.z, sv.w};
            const int dd[4] = {dv.x, dv.y, dv.z, dv.w};
            #pragma unroll
            for (int k = 0; k < 4; ++k) {
                const int b = dd[k] >> 8;
                const int r = atomicAdd(&sh.a.cnt2[b], 1);
                sh.a.buf[sh.a.excl[b] + r] = (unsigned int)ss[k]
                    | ((unsigned int)(dd[k] & 255) << 16);
            }
        }
        __syncthreads();
        // coalesced flush into this block's OWN region
        for (int i = t * 4; i < cnt; i += 2048)
            *(int4*)(pairs + base + i) = *(const int4*)(sh.a.buf + i);
    } else {
        lin_block(blockIdx.x - NB_A, x, W, att_s, att_d, xlh, a_src, a_dst, sh.l.wh);
    }
}

// ---------------------------------------------------------------------------
// K2: blocks [0, NBUCK) = binB v3; blocks [NBUCK, P2_NB) = lin part 2.
// binB v3: two coalesced wave-per-run walks over this bucket's runs
// (wave w takes runs w, w+8, ...): pass 1 histograms dst&255; after the
// LDS scan, pass 2 re-walks (L2-hot) scattering into node-sorted LDS
// staging; coalesced flush to csr segment. No binary search, no global
// atomics. Block 0 zeroes BN accumulators.
// ---------------------------------------------------------------------------
__global__ __launch_bounds__(512) void k_phase2(
        const unsigned int* __restrict__ pairs, const unsigned int* __restrict__ meta,
        unsigned short* __restrict__ csr, int2* __restrict__ nrange,
        float* __restrict__ gsums,
        const float* __restrict__ x, const float* __restrict__ W,
        const float* __restrict__ att_s, const float* __restrict__ att_d,
        __half* __restrict__ xlh, float* __restrict__ a_src,
        float* __restrict__ a_dst) {
    __shared__ union { BinBShm b; LinShm l; } sh;
    const int t = threadIdx.x;

    if (blockIdx.x < NBUCK) {
        const int b = blockIdx.x;
        if (b == 0 && t < 256) gsums[t] = 0.f;

        // meta column: run lengths/offsets of bucket b in every chunk
        if (t < 256) {
            int len = 0, off = 0;
            if (t < NB_A) {
                const unsigned int m = meta[(size_t)t * NBUCK + b];
                len = (int)(m & 0xFFFF);
                off = (int)(m >> 16);
            }
            sh.b.la[t] = len; sh.b.ea[t] = off;
            sh.b.hist[t] = 0; sh.b.cnt2[t] = 0;
        }
        __syncthreads();

        const int wave = t >> 6, lane = t & 63;

        // pass 1: per-node histogram via coalesced run-walk
        for (int r = wave; r < NB_A; r += 8) {
            const int len = sh.b.la[r];
            const unsigned int* src = pairs + (size_t)r * CHUNK + sh.b.ea[r];
            for (int j = lane; j < len; j += 64)
                atomicAdd(&sh.b.hist[(src[j] >> 16) & 255], 1);
        }
        __syncthreads();
        if (t < 256) sh.b.sc[t] = sh.b.hist[t];
        __syncthreads();
        for (int d = 1; d < 256; d <<= 1) {
            int xo = 0;
            if (t < 256 && t >= d) xo = sh.b.sc[t - d];
            __syncthreads();
            if (t < 256) sh.b.sc[t] += xo;
            __syncthreads();
        }
        if (t < 256) {
            sh.b.excl[t] = sh.b.sc[t] - sh.b.hist[t];
            const int node = (b << 8) + t;
            if (node < N_NODES) {
                int2 rg;
                rg.x = b * SEGCAP + sh.b.excl[t];
                rg.y = rg.x + sh.b.hist[t];
                nrange[node] = rg;
            }
        }
        __syncthreads();
        const int cnt = sh.b.sc[255];       // total edges in this bucket

        // pass 2: scatter into node-sorted LDS staging (src L2-hot now)
        for (int r = wave; r < NB_A; r += 8) {
            const int len = sh.b.la[r];
            const unsigned int* src = pairs + (size_t)r * CHUNK + sh.b.ea[r];
            for (int j = lane; j < len; j += 64) {
                const unsigned int u = src[j];
                const int dl = (u >> 16) & 255;
                const int p = atomicAdd(&sh.b.cnt2[dl], 1);
                sh.b.out[sh.b.excl[dl] + p] = (unsigned short)(u & 0xFFFF);
            }
        }
        __syncthreads();
        // coalesced flush into this bucket's private csr window
        for (int i = t; i < cnt; i += 512)
            csr[(size_t)b * SEGCAP + i] = sh.b.out[i];
    } else {
        lin_block(LIN_K1 + (int)blockIdx.x - NBUCK, x, W, att_s, att_d,
                  xlh, a_src, a_dst, sh.l.wh);
    }
}

// ---------------------------------------------------------------------------
// K3 v9 (unchanged, proven 61 µs): fused softmax + aggregation. One node per
// wave, 4 edge-groups x 16 lanes, lane covers 8 channels via one f16x8
// gather; 16-edge main loop. Logits pre-scaled by 1/ln2 -> bare exp2f.
// ---------------------------------------------------------------------------
#define AGG_NB (N_NODES / 4)   // 12500

__global__ void k_aggr9(const int2* __restrict__ nrange,
                        const unsigned short* __restrict__ csr,
                        const float* __restrict__ a_src, const float* __restrict__ a_dst,
                        const __half* __restrict__ xlh, float* __restrict__ y) {
    const int d = blockIdx.x * 4 + (threadIdx.x >> 6);
    const int lane = threadIdx.x & 63;
    const int g = lane >> 4;        // edge sub-group 0..3
    const int cl = lane & 15;       // channel slot: channels [cl*8, cl*8+8)
    const int h = cl >> 1;          // head owning this slot (OUT_C=16)
    const int2 rg = nrange[d];
    const int lo = rg.x, hi = rg.y;
    const float ad = a_dst[d * HEADS + h];

    float acc[8];
    #pragma unroll
    for (int k = 0; k < 8; ++k) acc[k] = 0.f;
    float dsum = 0.f;

    int i = lo;
    for (; i + 16 <= hi; i += 16) {
        const int s0 = csr[i + g];
        const int s1 = csr[i + 4 + g];
        const int s2 = csr[i + 8 + g];
        const int s3 = csr[i + 12 + g];
        const float as0 = a_src[s0 * HEADS + h];
        const float as1 = a_src[s1 * HEADS + h];
        const float as2 = a_src[s2 * HEADS + h];
        const float as3 = a_src[s3 * HEADS + h];
        const f16x8 x0 = *(const f16x8*)(xlh + (size_t)s0 * DIM + cl * 8);
        const f16x8 x1 = *(const f16x8*)(xlh + (size_t)s1 * DIM + cl * 8);
        const f16x8 x2 = *(const f16x8*)(xlh + (size_t)s2 * DIM + cl * 8);
        const f16x8 x3 = *(const f16x8*)(xlh + (size_t)s3 * DIM + cl * 8);
        const float e0 = as0 + ad;
        const float e1 = as1 + ad;
        const float e2 = as2 + ad;
        const float e3 = as3 + ad;
        const float w0 = exp2f(fmaxf(e0, NEG_SLOPE * e0));
        const float w1 = exp2f(fmaxf(e1, NEG_SLOPE * e1));
        const float w2 = exp2f(fmaxf(e2, NEG_SLOPE * e2));
        const float w3 = exp2f(fmaxf(e3, NEG_SLOPE * e3));
        dsum += (w0 + w1) + (w2 + w3);
        #pragma unroll
        for (int k = 0; k < 8; ++k) acc[k] = fmaf(w0, (float)x0[k], acc[k]);
        #pragma unroll
        for (int k = 0; k < 8; ++k) acc[k] = fmaf(w1, (float)x1[k], acc[k]);
        #pragma unroll
        for (int k = 0; k < 8; ++k) acc[k] = fmaf(w2, (float)x2[k], acc[k]);
        #pragma unroll
        for (int k = 0; k < 8; ++k) acc[k] = fmaf(w3, (float)x3[k], acc[k]);
    }
    for (; i + 8 <= hi; i += 8) {
        const int s0 = csr[i + g];
        const int s1 = csr[i + 4 + g];
        const float as0 = a_src[s0 * HEADS + h];
        const float as1 = a_src[s1 * HEADS + h];
        const f16x8 x0 = *(const f16x8*)(xlh + (size_t)s0 * DIM + cl * 8);
        const f16x8 x1 = *(const f16x8*)(xlh + (size_t)s1 * DIM + cl * 8);
        const float e0 = as0 + ad;
        const float e1 = as1 + ad;
        const float w0 = exp2f(fmaxf(e0, NEG_SLOPE * e0));
        const float w1 = exp2f(fmaxf(e1, NEG_SLOPE * e1));
        dsum += w0 + w1;
        #pragma unroll
        for (int k = 0; k < 8; ++k) acc[k] = fmaf(w0, (float)x0[k], acc[k]);
        #pragma unroll
        for (int k = 0; k < 8; ++k) acc[k] = fmaf(w1, (float)x1[k], acc[k]);
    }
    for (; i < hi; i += 4) {
        const int idx = i + g;
        const int sv = csr[min(idx, hi - 1)];
        const float e = a_src[sv * HEADS + h] + ad;
        const f16x8 xv = *(const f16x8*)(xlh + (size_t)sv * DIM + cl * 8);
        float w = exp2f(fmaxf(e, NEG_SLOPE * e));
        if (idx >= hi) w = 0.f;
        dsum += w;
        #pragma unroll
        for (int k = 0; k < 8; ++k) acc[k] = fmaf(w, (float)xv[k], acc[k]);
    }
    #pragma unroll
    for (int k = 0; k < 8; ++k) {
        acc[k] += __shfl_xor(acc[k], 16);
        acc[k] += __shfl_xor(acc[k], 32);
    }
    dsum += __shfl_xor(dsum, 16);
    dsum += __shfl_xor(dsum, 32);
    const float inv = 1.f / (dsum + 1e-16f);
    float2 o;
    o.x = acc[2 * g] * inv;
    o.y = acc[2 * g + 1] * inv;
    *(float2*)(y + (size_t)d * DIM + cl * 8 + g * 2) = o;
}

// ---------------------------------------------------------------------------
// BN stats over h = y + bias (512 blocks x 128 threads)
// ---------------------------------------------------------------------------
__global__ void k_stats(const float* __restrict__ y, const float* __restrict__ bias,
                        float* __restrict__ gsums) {
    const int c = threadIdx.x;
    const float b = bias[c];
    float s = 0.f, ss = 0.f;
    for (int n = blockIdx.x; n < N_NODES; n += gridDim.x) {
        const float h = y[n * DIM + c] + b;
        s += h;
        ss += h * h;
    }
    atomicAdd(&gsums[c], s);
    atomicAdd(&gsums[DIM + c], ss);
}

// ---------------------------------------------------------------------------
// K4: y = x + relu((y + bias - mean) * rsqrt(var+eps) * gamma + beta)
// ---------------------------------------------------------------------------
__global__ void k_final(float* __restrict__ y, const float* __restrict__ x,
                        const float* __restrict__ sums, const float* __restrict__ sumsq,
                        const float* __restrict__ gamma, const float* __restrict__ beta,
                        const float* __restrict__ bias) {
    const int q = blockIdx.x * blockDim.x + threadIdx.x;
    const int cq = q & (DIM / 4 - 1);
    const float4 sm = ((const float4*)sums)[cq];
    const float4 sq = ((const float4*)sumsq)[cq];
    const float4 gm = ((const float4*)gamma)[cq];
    const float4 bt = ((const float4*)beta)[cq];
    const float4 bs = ((const float4*)bias)[cq];
    float4 v = ((const float4*)y)[q];
    const float4 xv = ((const float4*)x)[q];
    const float inv_n = 1.f / (float)N_NODES;
#define BNC(c) { const float mean = sm.c * inv_n;                         \
                 const float var = sq.c * inv_n - mean * mean;            \
                 const float sc = rsqrtf(var + BN_EPS) * gm.c;            \
                 const float sh = bt.c + (bs.c - mean) * sc;              \
                 v.c = xv.c + fmaxf(v.c * sc + sh, 0.f); }
    BNC(x) BNC(y) BNC(z) BNC(w)
#undef BNC
    ((float4*)y)[q] = v;
}

extern "C" void kernel_launch(void* const* d_in, const int* in_sizes, int n_in,
                              void* d_out, int out_size, void* d_ws, size_t ws_size,
                              hipStream_t stream) {
    const float* x     = (const float*)d_in[0];
    const int*   ei    = (const int*)  d_in[1];
    const float* W     = (const float*)d_in[2];
    const float* att_s = (const float*)d_in[3];
    const float* att_d = (const float*)d_in[4];
    const float* bias  = (const float*)d_in[5];
    const float* gamma = (const float*)d_in[6];
    const float* beta  = (const float*)d_in[7];
    float* y = (float*)d_out;

    // workspace layout (~27.8 MiB)
    __half* xlh  = (__half*)d_ws;                          // 12.8 MB
    float* a_src = (float*)(xlh + (size_t)N_NODES * DIM);  // 1.6 MB
    float* a_dst = a_src + (size_t)N_NODES * HEADS;        // 1.6 MB
    float* sums  = a_dst + (size_t)N_NODES * HEADS;        // 512 B
    float* sumsq = sums  + DIM;                            // 512 B
    int2*  nrange = (int2*)(sumsq + DIM);                  // 400 KB
    unsigned int* meta  = (unsigned int*)(nrange + N_NODES);   // 196*196 u32 (154 KB)
    unsigned int* pairs = meta + (size_t)NB_A * NBUCK;         // 196*8192 u32 (6.4 MB)
    unsigned short* csr = (unsigned short*)(pairs + (size_t)NB_A * CHUNK); // 4.8 MB

    k_phase1<<<P1_NB, 512, 0, stream>>>(x, W, att_s, att_d, ei, meta, pairs,
                                        xlh, a_src, a_dst);
    k_phase2<<<P2_NB, 512, 0, stream>>>(pairs, meta, csr, nrange, sums,
                                        x, W, att_s, att_d, xlh, a_src, a_dst);
    k_aggr9<<<AGG_NB, 256, 0, stream>>>(nrange, csr, a_src, a_dst, xlh, y);
    k_stats<<<512, DIM, 0, stream>>>(y, bias, sums);
    k_final<<<(size_t)N_NODES * DIM / 4 / 256, 256, 0, stream>>>(y, x, sums, sumsq,
                                                                 gamma, beta, bias);
}